// Round 2
// baseline (182.238 us; speedup 1.0000x reference)
//
#include <hip/hip_runtime.h>
#include <cstdint>
#include <cstddef>

#define HW 524288      // H*W = 512*1024
#define HW4 131072     // float4/int4 groups per channel
#define NBIN 1024      // lovasz error histogram bins over [0,2]

// ws layout (bytes):
//   0      : double acc[16][8]  {cnt,cx,cy,sx,sy,sxx,syy,seedfg}     1024 B
//   1024   : double seedbg[2]                                          16 B
//   1040   : float  lov[16]                                            64 B
//   1104   : u32    ctr                                                 4 B
//   4096   : u64    ghist[16][NBIN]  (lo32=neg count, hi32=pos)    131072 B
//   262144 : u32    gdump[2][256][8][NBIN] per-block packed hists 16777216 B
// memset range: [0, 135168)   (gdump is fully overwritten, no zeroing)
// total ws use: ~17 MB (ws is 256 MiB per harness poison fill)

__device__ __forceinline__ float wred(float v) {
#pragma unroll
  for (int o = 32; o > 0; o >>= 1) v += __shfl_xor(v, o, 64);
  return v;
}

__device__ __forceinline__ float fsig(float x) {
  return __builtin_amdgcn_rcpf(1.f + __expf(-x));
}
__device__ __forceinline__ float ftanh(float x) {
  return 1.f - 2.f * __builtin_amdgcn_rcpf(__expf(2.f * x) + 1.f);
}

// ---------------- pass1: masked per-instance sums only ----------------
// grid (256, B), 256 thr, 2 float4 groups/thread (amortize reduction tail)
__global__ __launch_bounds__(256) void pass1(
    const float* __restrict__ pred, const int* __restrict__ masks,
    double* __restrict__ acc)
{
  const int b = blockIdx.y;
  const int tid = threadIdx.x;
  const float4* pb4 = (const float4*)(pred + (size_t)b * 12 * HW);
  const int4*   mk4 = (const int4*)(masks + (size_t)b * 8 * HW);

  float c[8] = {0}, cx[8] = {0}, cy[8] = {0}, sx[8] = {0}, sy[8] = {0},
        sxx[8] = {0}, syy[8] = {0};

#pragma unroll
  for (int k = 0; k < 2; k++) {
    const int g = blockIdx.x * 512 + k * 256 + tid;
    int idx = g << 2;
    int h = idx >> 10, w = idx & 1023;
    float4 p0 = pb4[g];
    float4 p1 = pb4[HW4 + g];
    float4 s0 = pb4[2 * HW4 + g];
    float4 s1 = pb4[3 * HW4 + g];
    int4 mv[8];
#pragma unroll
    for (int n = 0; n < 8; n++) mv[n] = mk4[n * HW4 + g];

    float p0v[4] = {p0.x, p0.y, p0.z, p0.w}, p1v[4] = {p1.x, p1.y, p1.z, p1.w};
    float s0v[4] = {s0.x, s0.y, s0.z, s0.w}, s1v[4] = {s1.x, s1.y, s1.z, s1.w};
    float exv[4], eyv[4];
#pragma unroll
    for (int j = 0; j < 4; j++) {
      exv[j] = ftanh(p0v[j]) + (float)((w + j) * (2.0 / 2047.0));
      eyv[j] = ftanh(p1v[j]) + (float)(h * (1.0 / 1023.0));
    }
#pragma unroll
    for (int n = 0; n < 8; n++) {
      int mvv[4] = {mv[n].x, mv[n].y, mv[n].z, mv[n].w};
#pragma unroll
      for (int j = 0; j < 4; j++) {
        float mf = (mvv[j] > 0) ? 1.f : 0.f;
        c[n] += mf; cx[n] += mf * exv[j]; cy[n] += mf * eyv[j];
        sx[n] += mf * s0v[j]; sy[n] += mf * s1v[j];
        sxx[n] += mf * s0v[j] * s0v[j]; syy[n] += mf * s1v[j] * s1v[j];
      }
    }
  }

  __shared__ float red[4][56];
  int lane = tid & 63, wid = tid >> 6;
#pragma unroll
  for (int n = 0; n < 8; n++) {
    float r0 = wred(c[n]),  r1 = wred(cx[n]), r2 = wred(cy[n]),
          r3 = wred(sx[n]), r4 = wred(sy[n]), r5 = wred(sxx[n]),
          r6 = wred(syy[n]);
    if (lane == 0) {
      red[wid][n * 7 + 0] = r0; red[wid][n * 7 + 1] = r1;
      red[wid][n * 7 + 2] = r2; red[wid][n * 7 + 3] = r3;
      red[wid][n * 7 + 4] = r4; red[wid][n * 7 + 5] = r5;
      red[wid][n * 7 + 6] = r6;
    }
  }
  __syncthreads();
  if (tid < 56) {
    float s = red[0][tid] + red[1][tid] + red[2][tid] + red[3][tid];
    int n = tid / 7, q = tid % 7;
    atomicAdd(&acc[((size_t)b * 8 + n) * 8 + q], (double)s);
  }
}

// ------- pass3 (pixel-major): each block handles ALL 8 instances -----------
// grid (256, B), 512 thr; block covers 2048 px = 512 float4 groups (1/thread).
// Reads p0/p1 ONCE per pixel (was 8x), computes tanh once. 8 packed hists in
// LDS (lo16=neg, hi16=pos; max 2048/block fits u16). Hists dumped non-atomic
// to gdump; pass4a reduces. Bin math identical to round-0 version -> integer
// hist counts identical -> lovasz path bit-identical.
__global__ __launch_bounds__(512) void pass3(
    const float* __restrict__ pred, const int* __restrict__ bbox,
    const int* __restrict__ masks, const int* __restrict__ cls_ids,
    double* __restrict__ acc, double* __restrict__ seedbg,
    unsigned* __restrict__ gdump)
{
  const int b = blockIdx.y;
  const int tid = threadIdx.x;
  __shared__ unsigned hist[8 * NBIN];   // 32 KB
  __shared__ float redf[8][9];

  uint4* h4 = (uint4*)hist;
  for (int j = tid; j < 2048; j += 512) h4[j] = make_uint4(0u, 0u, 0u, 0u);

  // per-instance uniform params (block-uniform; compiler keeps scalar)
  float cxp[8], cyp[8], sexp[8], seyp[8];
  int clsv[8];
#pragma unroll
  for (int n = 0; n < 8; n++) {
    const double* a = acc + ((size_t)b * 8 + n) * 8;
    double cs = a[0] < 1.0 ? 1.0 : a[0];
    cxp[n] = (float)(a[1] / cs);
    cyp[n] = (float)(a[2] / cs);
    sexp[n] = __expf((float)(a[3] / cs) * 10.f);
    seyp[n] = __expf((float)(a[4] / cs) * 10.f);
    clsv[n] = cls_ids[b * 8 + n];
  }
  const float4* pb4 = (const float4*)(pred + (size_t)b * 12 * HW);
  const int4*   mk4 = (const int4*)(masks + (size_t)b * 8 * HW);
  const int4*   bb4 = (const int4*)(bbox + (size_t)b * 9 * HW);
  __syncthreads();

  const int g = blockIdx.x * 512 + tid;
  const int idx = g << 2;
  const int h = idx >> 10, w = idx & 1023;

  float4 p0 = pb4[g];
  float4 p1 = pb4[HW4 + g];
  float ex[4], ey[4];
  {
    float p0v[4] = {p0.x, p0.y, p0.z, p0.w}, p1v[4] = {p1.x, p1.y, p1.z, p1.w};
#pragma unroll
    for (int j = 0; j < 4; j++) {
      ex[j] = ftanh(p0v[j]) + (float)((w + j) * (2.0 / 2047.0));
      ey[j] = ftanh(p1v[j]) + (float)(h * (1.0 / 1023.0));
    }
  }

  float sbg = 0.f;
  int lane = tid & 63, wid = tid >> 6;
#pragma unroll
  for (int n = 0; n < 8; n++) {
    int4   mv = mk4[n * HW4 + g];
    int4   bv = bb4[(1 + n) * HW4 + g];
    float4 sc = pb4[(4 + clsv[n]) * HW4 + g];   // seed ch for cls (cache-hot)
    float4 sb = pb4[(4 + n) * HW4 + g];         // bg-seed ch n
    int mvv[4] = {mv.x, mv.y, mv.z, mv.w}, bvv[4] = {bv.x, bv.y, bv.z, bv.w};
    float scv[4] = {sc.x, sc.y, sc.z, sc.w}, sbv[4] = {sb.x, sb.y, sb.z, sb.w};
    float sf = 0.f;
#pragma unroll
    for (int j = 0; j < 4; j++) {
      int m = (mvv[j] > 0) ? 1 : 0;
      float dx = ex[j] - cxp[n], dy = ey[j] - cyp[n];
      float d = __expf(-(dx * dx * sexp[n] + dy * dy * seyp[n]));
      float df = fsig(scv[j]) - d;
      sf += m ? df * df : 0.f;
      float s0 = fsig(sbv[j]);
      sbg += (bvv[j] == 0) ? s0 * s0 : 0.f;
      float e = m ? 2.f - 2.f * d : 2.f * d;
      int k = (int)(e * 512.f); k = k > (NBIN - 1) ? (NBIN - 1) : k;
      atomicAdd(&hist[n * NBIN + k], m ? 65536u : 1u);
    }
    float r = wred(sf);
    if (lane == 0) redf[wid][n] = r;
  }
  {
    float r = wred(sbg);
    if (lane == 0) redf[wid][8] = r;
  }
  __syncthreads();

  // non-atomic coalesced dump of the 8 packed hists (fully overwritten)
  uint4* dst = (uint4*)(gdump + ((size_t)(b * 256 + blockIdx.x) * 8) * NBIN);
  for (int j = tid; j < 2048; j += 512) dst[j] = h4[j];

  if (tid < 9) {
    float t = 0.f;
    for (int w2 = 0; w2 < 8; w2++) t += redf[w2][tid];
    if (tid < 8)
      atomicAdd(&acc[((size_t)b * 8 + tid) * 8 + 7], (double)t);
    else
      atomicAdd(&seedbg[b], (double)t);
  }
}

// ------- pass4a: reduce per-block hist dumps into ghist (u64 packed) --------
// grid (256) = 16 segs x 16 chunks, 256 thr; each block reduces 16 x-blocks.
__global__ __launch_bounds__(256) void pass4a(
    const unsigned* __restrict__ gdump, unsigned long long* __restrict__ ghist)
{
  const int seg = blockIdx.x >> 4;          // 0..15 = b*8+n
  const int chunk = blockIdx.x & 15;
  const int b = seg >> 3, n = seg & 7;
  const int tid = threadIdx.x;

  unsigned neg[4] = {0, 0, 0, 0}, pos[4] = {0, 0, 0, 0};
#pragma unroll
  for (int xb = 0; xb < 16; xb++) {
    int blk = chunk * 16 + xb;
    const uint4 v = ((const uint4*)gdump)[(((size_t)b * 256 + blk) * 8 + n) * 256 + tid];
    neg[0] += v.x & 0xffffu; pos[0] += v.x >> 16;
    neg[1] += v.y & 0xffffu; pos[1] += v.y >> 16;
    neg[2] += v.z & 0xffffu; pos[2] += v.z >> 16;
    neg[3] += v.w & 0xffffu; pos[3] += v.w >> 16;
  }
  unsigned long long* gh = ghist + (size_t)seg * NBIN;
#pragma unroll
  for (int i = 0; i < 4; i++) {
    if (neg[i] | pos[i])
      atomicAdd(&gh[tid * 4 + i],
                (unsigned long long)neg[i] | ((unsigned long long)pos[i] << 32));
  }
}

// ------- pass4: parallel closed-form Lovász + last-block final combine -------
// 16 blocks x 256 thr, 4 bins/thread. positive run at (p,C): grad = 1/(G+p-C);
// negative run n0: sum = (G-C)*(1/a - 1/(a+n0)), a = G+p-C.
__global__ __launch_bounds__(256) void pass4(
    const unsigned long long* __restrict__ ghist, const double* __restrict__ acc,
    const double* __restrict__ seedbg, const int* __restrict__ cls_ids,
    float* __restrict__ lov, unsigned* __restrict__ ctr,
    float* __restrict__ out)
{
  const int seg = blockIdx.x;
  const int tid = threadIdx.x;
  const int lane = tid & 63, wid = tid >> 6;
  __shared__ __align__(16) unsigned lh[NBIN * 2];   // [2k]=neg, [2k+1]=pos (8 KB)
  __shared__ unsigned wc[4], wp[4];
  __shared__ double sred[4];

  const uint4* gh4 = (const uint4*)(ghist + (size_t)seg * NBIN);
#pragma unroll
  for (int i = 0; i < 2; i++)
    ((uint4*)lh)[i * 256 + tid] = gh4[i * 256 + tid];
  __syncthreads();

  double G = acc[seg * 8 + 0];

  unsigned cntT = 0, posT = 0;
#pragma unroll
  for (int i = 0; i < 4; i++) {
    int kk = (NBIN - 1) - tid * 4 - i;
    unsigned h0 = lh[2 * kk], h1 = lh[2 * kk + 1];
    cntT += h0 + h1; posT += h1;
  }
  unsigned ic = cntT, ip = posT;
  for (int o = 1; o < 64; o <<= 1) {
    unsigned yc = __shfl_up(ic, o, 64), yp = __shfl_up(ip, o, 64);
    if (lane >= o) { ic += yc; ip += yp; }
  }
  if (lane == 63) { wc[wid] = ic; wp[wid] = ip; }
  __syncthreads();
  unsigned oc = 0, op = 0;
  for (int w2 = 0; w2 < wid; w2++) { oc += wc[w2]; op += wp[w2]; }
  unsigned p = oc + ic - cntT, C = op + ip - posT;   // exclusive prefix

  double S = 0.0;
#pragma unroll
  for (int i = 0; i < 4; i++) {
    int kk = (NBIN - 1) - tid * 4 - i;
    unsigned n1 = lh[2 * kk + 1], n0 = lh[2 * kk];
    double ec = (kk + 0.5) * (1.0 / 512.0);   // bin-center error value
    if (n1) {
      S += (double)n1 * ec / (G + (double)(p - C));
      p += n1; C += n1;
    }
    if (n0) {
      double rem = G - (double)C;
      if (rem > 0.0) {
        double aa = G + (double)(p - C);
        S += ec * rem * (1.0 / aa - 1.0 / (aa + (double)n0));
      }
      p += n0;
    }
  }
#pragma unroll
  for (int o = 32; o > 0; o >>= 1) S += __shfl_xor(S, o, 64);
  if (lane == 0) sred[wid] = S;
  __syncthreads();

  if (tid == 0) {
    double St = sred[0] + sred[1] + sred[2] + sred[3];
    atomicExch(&lov[seg], (float)St);
    __threadfence();
    unsigned old = atomicAdd(ctr, 1u);
    if (old == 15u) {                 // last block: final combine
      __threadfence();
      const float FG[8] = {10.f, 10.f, 10.f, 40.f, 80.f, 100.f, 60.f, 20.f};
      double total = 0.0;
      for (int b = 0; b < 2; b++) {
        double obj = 0, inst = 0, varl = 0, sfg = 0;
        for (int n = 0; n < 8; n++) {
          int s = b * 8 + n;
          const double* a = acc + s * 8;
          double cnt = a[0];
          double cs = cnt < 1.0 ? 1.0 : cnt;
          double smx = a[3] / cs, smy = a[4] / cs;
          double var = ((a[5] - cnt * smx * smx) + (a[6] - cnt * smy * smy)) /
                       (2.0 * cs);
          double v = (cnt >= 128.0) ? 1.0 : 0.0;
          double lv = (double)atomicAdd(&lov[s], 0.0f);   // coherent read
          obj += v;
          inst += lv * v;
          varl += var * v;
          sfg += (double)FG[cls_ids[s]] * a[7] * v;
        }
        double objs = obj < 1.0 ? 1.0 : obj;
        double seedl = (seedbg[b] + sfg) / (double)HW;
        total += inst / objs + 10.0 * (varl / objs) + seedl;
      }
      out[0] = (float)(0.5 * total);
    }
  }
}

extern "C" void kernel_launch(void* const* d_in, const int* in_sizes, int n_in,
                              void* d_out, int out_size, void* d_ws, size_t ws_size,
                              hipStream_t stream)
{
  (void)in_sizes; (void)n_in; (void)out_size; (void)ws_size;
  const float* pred  = (const float*)d_in[0];
  const int*   bbox  = (const int*)d_in[1];
  const int*   masks = (const int*)d_in[2];
  const int*   cls   = (const int*)d_in[3];

  char* ws = (char*)d_ws;
  double*             acc    = (double*)(ws + 0);       // 128 doubles
  double*             seedbg = (double*)(ws + 1024);    // 2 doubles
  float*              lov    = (float*)(ws + 1040);     // 16 floats
  unsigned*           ctr    = (unsigned*)(ws + 1104);  // 1 u32
  unsigned long long* ghist  = (unsigned long long*)(ws + 4096);   // 16*NBIN u64
  unsigned*           gdump  = (unsigned*)(ws + 262144);           // 16 MB

  hipMemsetAsync(d_ws, 0, 135168, stream);
  pass1<<<dim3(256, 2), 256, 0, stream>>>(pred, masks, acc);
  pass3<<<dim3(256, 2), 512, 0, stream>>>(pred, bbox, masks, cls, acc, seedbg, gdump);
  pass4a<<<256, 256, 0, stream>>>(gdump, ghist);
  pass4<<<16, 256, 0, stream>>>(ghist, acc, seedbg, cls, lov, ctr, (float*)d_out);
}